// Round 5
// baseline (40.239 us; speedup 1.0000x reference)
//
#include <hip/hip_runtime.h>

// PullbackMetric, 4 threads per pixel (each owns rows {2s, 2s+1} of the 8x8 mats).
// G[m][n] = dmu_m^T Si dmu_n + 0.5 * tr( (Si dSig_m) (Si dSig_n) )
// T = Si*dSx, U = Si*dSy (rows in registers). Cov traces via transposed
// writeback: Tt[k][i] = T[i][k] so column slices become vectorized row reads.
// LDS: slotA (dSx -> Tt), slotB (dSy -> Ut). dmu is register-only (direct mu loads).

constexpr int MSTRIDE = 68;   // 272 B slot stride: 16B-aligned, spreads banks (4p mod 32)

__global__ __launch_bounds__(256, 4) void pm4_kernel(
    const float* __restrict__ mu,
    const float* __restrict__ sigma,
    const float* __restrict__ sigma_inv,
    float* __restrict__ out)
{
    __shared__ float mA[64 * MSTRIDE];   // 17408 B
    __shared__ float mB[64 * MSTRIDE];   // 17408 B  (total 34816 B -> 4 blocks/CU)

    const int tid = threadIdx.x;
    const int s   = tid & 3;     // row-pair id: rows 2s, 2s+1
    const int p   = tid >> 2;    // pixel within block (0..63)

    // XCD-aware chunked swizzle: 4096 blocks, 8 XCDs, 512 contiguous logical blocks/XCD
    const int bid = blockIdx.x;
    const int swz = (bid & 7) * 512 + (bid >> 3);
    const int idx = swz * 64 + p;            // pixel 0..262143

    const int x = idx >> 9, y = idx & 511;
    const int ixp = (((x + 1) & 511) << 9) | y;
    const int ixm = (((x - 1) & 511) << 9) | y;
    const int iyp = (x << 9) | ((y + 1) & 511);
    const int iym = (x << 9) | ((y - 1) & 511);

    float* slotA = mA + p * MSTRIDE;
    float* slotB = mB + p * MSTRIDE;

    // ---------------- load Si rows 2s, 2s+1 (16 floats) ----------------
    float Si[16];
    {
        const float4* q = reinterpret_cast<const float4*>(sigma_inv + (size_t)idx * 64 + s * 16);
        #pragma unroll
        for (int k = 0; k < 4; ++k) {
            float4 v = q[k];
            Si[4*k+0] = v.x; Si[4*k+1] = v.y; Si[4*k+2] = v.z; Si[4*k+3] = v.w;
        }
    }

    // ---------------- full dmu vectors, register-only (mu is L1/L2-hot) ----------------
    float dmu0[8], dmu1[8];
    {
        const float4* mxp = reinterpret_cast<const float4*>(mu + (size_t)ixp * 8);
        const float4* mxm = reinterpret_cast<const float4*>(mu + (size_t)ixm * 8);
        const float4* myp = reinterpret_cast<const float4*>(mu + (size_t)iyp * 8);
        const float4* mym = reinterpret_cast<const float4*>(mu + (size_t)iym * 8);
        #pragma unroll
        for (int k = 0; k < 2; ++k) {
            float4 a = mxp[k], b = mxm[k], c = myp[k], d = mym[k];
            dmu0[4*k+0] = (a.x - b.x) * 0.5f;
            dmu0[4*k+1] = (a.y - b.y) * 0.5f;
            dmu0[4*k+2] = (a.z - b.z) * 0.5f;
            dmu0[4*k+3] = (a.w - b.w) * 0.5f;
            dmu1[4*k+0] = (c.x - d.x) * 0.5f;
            dmu1[4*k+1] = (c.y - d.y) * 0.5f;
            dmu1[4*k+2] = (c.z - d.z) * 0.5f;
            dmu1[4*k+3] = (c.w - d.w) * 0.5f;
        }
    }
    // select dmu components of this thread's rows (compile-time unrolled -> cndmask, no scratch)
    float d0a = 0.f, d0b = 0.f, d1a = 0.f, d1b = 0.f;
    #pragma unroll
    for (int c = 0; c < 8; ++c) {
        if (2 * s == c)     { d0a = dmu0[c]; d1a = dmu1[c]; }
        if (2 * s + 1 == c) { d0b = dmu0[c]; d1b = dmu1[c]; }
    }

    // ---------------- stage dSx rows -> slotA, dSy rows -> slotB ----------------
    {
        const float4* axp = reinterpret_cast<const float4*>(sigma + (size_t)ixp * 64 + s * 16);
        const float4* axm = reinterpret_cast<const float4*>(sigma + (size_t)ixm * 64 + s * 16);
        const float4* ayp = reinterpret_cast<const float4*>(sigma + (size_t)iyp * 64 + s * 16);
        const float4* aym = reinterpret_cast<const float4*>(sigma + (size_t)iym * 64 + s * 16);
        float4* wA = reinterpret_cast<float4*>(slotA + s * 16);
        float4* wB = reinterpret_cast<float4*>(slotB + s * 16);
        #pragma unroll
        for (int k = 0; k < 4; ++k) {
            float4 a = axp[k], b = axm[k];
            float4 r;
            r.x = (a.x - b.x) * 0.5f; r.y = (a.y - b.y) * 0.5f;
            r.z = (a.z - b.z) * 0.5f; r.w = (a.w - b.w) * 0.5f;
            wA[k] = r;
            float4 c = ayp[k], d = aym[k];
            float4 r2;
            r2.x = (c.x - d.x) * 0.5f; r2.y = (c.y - d.y) * 0.5f;
            r2.z = (c.z - d.z) * 0.5f; r2.w = (c.w - d.w) * 0.5f;
            wB[k] = r2;
        }
    }

    __syncthreads();   // staging complete

    // ---------------- T rows = Si_rows * dSx ; U rows = Si_rows * dSy ----------------
    float T0[8] = {0}, T1[8] = {0}, U0[8] = {0}, U1[8] = {0};
    #pragma unroll
    for (int j = 0; j < 8; ++j) {
        float a0 = Si[j], a1 = Si[8 + j];
        float bx[8], by[8];
        *reinterpret_cast<float4*>(&bx[0]) = *reinterpret_cast<const float4*>(slotA + j * 8);
        *reinterpret_cast<float4*>(&bx[4]) = *reinterpret_cast<const float4*>(slotA + j * 8 + 4);
        *reinterpret_cast<float4*>(&by[0]) = *reinterpret_cast<const float4*>(slotB + j * 8);
        *reinterpret_cast<float4*>(&by[4]) = *reinterpret_cast<const float4*>(slotB + j * 8 + 4);
        #pragma unroll
        for (int k = 0; k < 8; ++k) {
            T0[k] = fmaf(a0, bx[k], T0[k]);
            T1[k] = fmaf(a1, bx[k], T1[k]);
            U0[k] = fmaf(a0, by[k], U0[k]);
            U1[k] = fmaf(a1, by[k], U1[k]);
        }
    }

    // ---------------- mean terms (register-only) ----------------
    float m00, m01, m11;
    {
        float t00 = 0, t01 = 0, t10 = 0, t11 = 0;  // (Si dmu_n)[row 2s], [row 2s+1]
        #pragma unroll
        for (int j = 0; j < 8; ++j) {
            t00 = fmaf(Si[j],     dmu0[j], t00);
            t01 = fmaf(Si[j],     dmu1[j], t01);
            t10 = fmaf(Si[8 + j], dmu0[j], t10);
            t11 = fmaf(Si[8 + j], dmu1[j], t11);
        }
        m00 = d0a * t00 + d0b * t10;
        m01 = d0a * t01 + d0b * t11;
        m11 = d1a * t01 + d1b * t11;
    }

    __syncthreads();   // all matmul reads of slotA/slotB done

    // ---------------- transposed writeback: Tt[k][i]=T[i][k] -> slotA, Ut -> slotB ----------------
    // Thread owns T columns 2s,2s+1 -> float2 writes at row k, offset 2s.
    {
        #pragma unroll
        for (int k = 0; k < 8; ++k) {
            float2 vt; vt.x = T0[k]; vt.y = T1[k];
            float2 vu; vu.x = U0[k]; vu.y = U1[k];
            *reinterpret_cast<float2*>(slotA + k * 8 + 2 * s) = vt;
            *reinterpret_cast<float2*>(slotB + k * 8 + 2 * s) = vu;
        }
    }

    __syncthreads();   // Tt, Ut visible

    // ---------------- cov partials via vectorized row reads of Tt/Ut ----------------
    // c00 = dot(T0, Tt[2s]) + dot(T1, Tt[2s+1]); c01 = dot(T0, Ut[2s]) + dot(T1, Ut[2s+1]);
    // c11 = dot(U0, Ut[2s]) + dot(U1, Ut[2s+1]).
    float c00 = 0, c01 = 0, c11 = 0;
    {
        float tt0[8], tt1[8], ut0[8], ut1[8];
        *reinterpret_cast<float4*>(&tt0[0]) = *reinterpret_cast<const float4*>(slotA + (2*s)   * 8);
        *reinterpret_cast<float4*>(&tt0[4]) = *reinterpret_cast<const float4*>(slotA + (2*s)   * 8 + 4);
        *reinterpret_cast<float4*>(&tt1[0]) = *reinterpret_cast<const float4*>(slotA + (2*s+1) * 8);
        *reinterpret_cast<float4*>(&tt1[4]) = *reinterpret_cast<const float4*>(slotA + (2*s+1) * 8 + 4);
        *reinterpret_cast<float4*>(&ut0[0]) = *reinterpret_cast<const float4*>(slotB + (2*s)   * 8);
        *reinterpret_cast<float4*>(&ut0[4]) = *reinterpret_cast<const float4*>(slotB + (2*s)   * 8 + 4);
        *reinterpret_cast<float4*>(&ut1[0]) = *reinterpret_cast<const float4*>(slotB + (2*s+1) * 8);
        *reinterpret_cast<float4*>(&ut1[4]) = *reinterpret_cast<const float4*>(slotB + (2*s+1) * 8 + 4);
        #pragma unroll
        for (int k = 0; k < 8; ++k) {
            c00 = fmaf(T0[k], tt0[k], c00); c00 = fmaf(T1[k], tt1[k], c00);
            c01 = fmaf(T0[k], ut0[k], c01); c01 = fmaf(T1[k], ut1[k], c01);
            c11 = fmaf(U0[k], ut0[k], c11); c11 = fmaf(U1[k], ut1[k], c11);
        }
    }

    // ---------------- combine, 4-lane reduce, write ----------------
    float g0 = m00 + 0.5f * c00;
    float g1 = m01 + 0.5f * c01;
    float g3 = m11 + 0.5f * c11;
    g0 += __shfl_xor(g0, 1); g0 += __shfl_xor(g0, 2);
    g1 += __shfl_xor(g1, 1); g1 += __shfl_xor(g1, 2);
    g3 += __shfl_xor(g3, 1); g3 += __shfl_xor(g3, 2);

    float val = (s == 0) ? g0 : ((s == 3) ? g3 : g1);
    out[(size_t)idx * 4 + s] = val;
}

extern "C" void kernel_launch(void* const* d_in, const int* in_sizes, int n_in,
                              void* d_out, int out_size, void* d_ws, size_t ws_size,
                              hipStream_t stream) {
    const float* mu        = (const float*)d_in[0];
    const float* sigma     = (const float*)d_in[1];
    const float* sigma_inv = (const float*)d_in[2];
    float* out = (float*)d_out;

    // 262144 pixels * 4 threads / 256 = 4096 blocks (divisible by 8 -> bijective swizzle)
    pm4_kernel<<<4096, 256, 0, stream>>>(mu, sigma, sigma_inv, out);
}